// Round 12
// baseline (508.938 us; speedup 1.0000x reference)
//
#include <hip/hip_runtime.h>

#define TT 64
#define CC 384
#define NH 6
#define HID 1536
#define LDX 392   // attn: padded cols for 64x384 bf16 tiles
#define LDH 72    // attn head tiles (144B stride)

typedef __bf16 bf16x8 __attribute__((ext_vector_type(8)));
typedef float f32x4 __attribute__((ext_vector_type(4)));
typedef unsigned short us8 __attribute__((ext_vector_type(8)));

#define MFMA(a, b, c) __builtin_amdgcn_mfma_f32_16x16x32_bf16(a, b, c, 0, 0, 0)
#define WAITVM(N) asm volatile("s_waitcnt vmcnt(" #N ")" ::: "memory")

static __device__ __forceinline__ unsigned short f2bf(float f) {
  unsigned u = __builtin_bit_cast(unsigned, f);
  u += 0x7FFFu + ((u >> 16) & 1u);
  return (unsigned short)(u >> 16);
}
static __device__ __forceinline__ float bf2f(unsigned short h) {
  unsigned u = ((unsigned)h) << 16;
  return __builtin_bit_cast(float, u);
}
static __device__ __forceinline__ bf16x8 ld8(const unsigned short* p) {
  return __builtin_bit_cast(bf16x8, *reinterpret_cast<const us8*>(p));
}
// async global->LDS, 16B per lane; lds dest = wave-uniform base + lane*16
static __device__ __forceinline__ void glds16(const unsigned short* g, unsigned short* l) {
  __builtin_amdgcn_global_load_lds(
      (const __attribute__((address_space(1))) void*)g,
      (__attribute__((address_space(3))) void*)l, 16, 0, 0);
}

// ---- weight prep: fp32 -> bf16, transposed to [n][k] for MFMA B-frags ----
__global__ void prep_w(const float* __restrict__ Wq, const float* __restrict__ Wk,
                       const float* __restrict__ Wv, const float* __restrict__ Wo,
                       const float* __restrict__ W1, const float* __restrict__ W2,
                       unsigned short* __restrict__ ws) {
  const int T0 = 1152 * 384;            // Wqkv [h*192+j][k]
  const int T1 = T0 + 384 * 384;        // WoT  [n][k]
  const int T2 = T1 + 1536 * 384;       // W1T  [n][k]
  const int T3 = T2 + 384 * 1536;       // W2T  [n][k]
  for (int i = blockIdx.x * blockDim.x + threadIdx.x; i < T3; i += gridDim.x * blockDim.x) {
    float v;
    if (i < T0) {
      int n = i / 384, k = i % 384;
      int hh = n / 192, j = n % 192;
      const float* W = (j < 64) ? Wq : (j < 128) ? Wk : Wv;
      int d = (j < 64) ? j : (j < 128) ? j - 64 : j - 128;
      v = W[((size_t)hh * 384 + k) * 64 + d];
    } else if (i < T1) {
      int i2 = i - T0; int n = i2 / 384, k = i2 % 384;
      v = Wo[(size_t)k * 384 + n];
    } else if (i < T2) {
      int i2 = i - T1; int n = i2 / 384, k = i2 % 384;
      v = W1[(size_t)k * 1536 + n];
    } else {
      int i2 = i - T2; int n = i2 / 1536, k = i2 % 1536;
      v = W2[(size_t)k * 384 + n];
    }
    ws[i] = f2bf(v);
  }
}

// ---- kernel A: LN1 + attention + per-head proj accumulation + residual -> x2 (=d_out, fp32)
__global__ __launch_bounds__(256, 2)
void attn_fwd(const float* __restrict__ x,
              const float* __restrict__ ln1g, const float* __restrict__ ln1b,
              const float* __restrict__ bo,
              const unsigned short* __restrict__ Wqkv,
              const unsigned short* __restrict__ WoT,
              float* __restrict__ x2) {
  __shared__ unsigned short sXN[TT * LDX];       // xn1 (bf16)
  __shared__ unsigned short sHEAD[3 * TT * LDH]; // q | k (later att_h) | vT
  unsigned short* sQ = sHEAD;                    // q [t][d]; later P [t][s]
  unsigned short* sK = sHEAD + TT * LDH;         // k [s][d]; later att_h [t][d]
  unsigned short* sV = sHEAD + 2 * TT * LDH;     // vT [d][s]

  const int b = blockIdx.x;
  const int tid = threadIdx.x;
  const int wv = tid >> 6;
  const int ln = tid & 63;
  const int l16 = ln & 15;
  const int lg = ln >> 4;
  const float* xb = x + (size_t)b * TT * CC;
  const f32x4 Z4 = {0.f, 0.f, 0.f, 0.f};

  // ---------- LN1 ----------
#pragma unroll 1
  for (int r = wv * 16; r < wv * 16 + 16; ++r) {
    float v[6], s = 0.f, sq = 0.f;
#pragma unroll
    for (int j = 0; j < 6; ++j) { v[j] = xb[r * CC + ln + 64 * j]; s += v[j]; sq += v[j] * v[j]; }
#pragma unroll
    for (int off = 32; off; off >>= 1) { s += __shfl_xor(s, off); sq += __shfl_xor(sq, off); }
    float mu = s * (1.f / CC);
    float rs = rsqrtf(sq * (1.f / CC) - mu * mu + 1e-5f);
#pragma unroll
    for (int j = 0; j < 6; ++j) {
      int c = ln + 64 * j;
      sXN[r * LDX + c] = f2bf((v[j] - mu) * rs * ln1g[c] + ln1b[c]);
    }
  }
  __syncthreads();

  f32x4 pacc[4][6];
#pragma unroll
  for (int m = 0; m < 4; ++m)
#pragma unroll
    for (int c = 0; c < 6; ++c) pacc[m][c] = Z4;

  const unsigned short* prow[6];
#pragma unroll
  for (int c = 0; c < 6; ++c)
    prow[c] = WoT + (size_t)(wv * 96 + c * 16 + l16) * CC + 8 * lg;

#pragma unroll 1
  for (int h = 0; h < NH; ++h) {
    const unsigned short* wrow[3];
#pragma unroll
    for (int c = 0; c < 3; ++c)
      wrow[c] = Wqkv + (size_t)(h * 192 + wv * 48 + c * 16 + l16) * CC + 8 * lg;

    f32x4 qacc[4][3];
#pragma unroll
    for (int m = 0; m < 4; ++m)
#pragma unroll
      for (int c = 0; c < 3; ++c) qacc[m][c] = Z4;

    // depth-2 B prefetch pipeline
    bf16x8 bpre[2][3];
#pragma unroll
    for (int c = 0; c < 3; ++c) bpre[0][c] = ld8(wrow[c] + 0);
#pragma unroll
    for (int c = 0; c < 3; ++c) bpre[1][c] = ld8(wrow[c] + 32);
#pragma unroll
    for (int kk = 0; kk < CC; kk += 32) {
      const int slot = (kk >> 5) & 1;
      bf16x8 bcur[3];
#pragma unroll
      for (int c = 0; c < 3; ++c) bcur[c] = bpre[slot][c];
      if (kk + 64 < CC) {
#pragma unroll
        for (int c = 0; c < 3; ++c) bpre[slot][c] = ld8(wrow[c] + kk + 64);
      }
      bf16x8 a[4];
#pragma unroll
      for (int m = 0; m < 4; ++m)
        a[m] = ld8(&sXN[(m * 16 + l16) * LDX + kk + 8 * lg]);
      __builtin_amdgcn_s_setprio(1);
#pragma unroll
      for (int c = 0; c < 3; ++c)
#pragma unroll
        for (int m = 0; m < 4; ++m) qacc[m][c] = MFMA(a[m], bcur[c], qacc[m][c]);
      __builtin_amdgcn_s_setprio(0);
    }
    __syncthreads();  // B1
    // scatter: q [t][d], k [s][d], vT [d][s]
#pragma unroll
    for (int m = 0; m < 4; ++m)
#pragma unroll
      for (int c = 0; c < 3; ++c) {
        int n = wv * 48 + c * 16 + l16;
#pragma unroll
        for (int rg = 0; rg < 4; ++rg) {
          int t = m * 16 + lg * 4 + rg;
          unsigned short bv = f2bf(qacc[m][c][rg]);
          if (n < 64) sQ[t * LDH + n] = bv;
          else if (n < 128) sK[t * LDH + (n - 64)] = bv;
          else sV[(n - 128) * LDH + t] = bv;
        }
      }
    __syncthreads();  // B2

    // ----- S = q.kT
    f32x4 sacc[4];
#pragma unroll
    for (int c = 0; c < 4; ++c) sacc[c] = Z4;
#pragma unroll
    for (int kk = 0; kk < 64; kk += 32) {
      bf16x8 a = ld8(&sQ[(wv * 16 + l16) * LDH + kk + 8 * lg]);
#pragma unroll
      for (int c = 0; c < 4; ++c) {
        bf16x8 bb = ld8(&sK[(c * 16 + l16) * LDH + kk + 8 * lg]);
        sacc[c] = MFMA(a, bb, sacc[c]);
      }
    }
    // causal softmax
#pragma unroll
    for (int rg = 0; rg < 4; ++rg) {
      int row = wv * 16 + lg * 4 + rg;
      float e[4], mx = -1e30f;
#pragma unroll
      for (int c = 0; c < 4; ++c) {
        int col = c * 16 + l16;
        float vv = sacc[c][rg] * 0.125f;
        e[c] = (col <= row) ? vv : -1e30f;
        mx = fmaxf(mx, e[c]);
      }
#pragma unroll
      for (int off = 8; off; off >>= 1) mx = fmaxf(mx, __shfl_xor(mx, off));
      float sum = 0.f;
#pragma unroll
      for (int c = 0; c < 4; ++c) {
        int col = c * 16 + l16;
        e[c] = (col <= row) ? __expf(e[c] - mx) : 0.f;
        sum += e[c];
      }
#pragma unroll
      for (int off = 8; off; off >>= 1) sum += __shfl_xor(sum, off);
      float inv = 1.f / sum;
#pragma unroll
      for (int c = 0; c < 4; ++c)
        sQ[row * LDH + c * 16 + l16] = f2bf(e[c] * inv);
    }

    // Preload ALL Wo B-frags for this head (latency hides under PV)
    bf16x8 pb[2][6];
#pragma unroll
    for (int s2 = 0; s2 < 2; ++s2)
#pragma unroll
      for (int c = 0; c < 6; ++c)
        pb[s2][c] = ld8(prow[c] + h * 64 + 32 * s2);

    // ----- out_h = P @ V
    f32x4 oacc[4];
#pragma unroll
    for (int c = 0; c < 4; ++c) oacc[c] = Z4;
#pragma unroll
    for (int kk = 0; kk < 64; kk += 32) {
      bf16x8 a = ld8(&sQ[(wv * 16 + l16) * LDH + kk + 8 * lg]);
#pragma unroll
      for (int c = 0; c < 4; ++c) {
        bf16x8 bb = ld8(&sV[(c * 16 + l16) * LDH + kk + 8 * lg]);
        oacc[c] = MFMA(a, bb, oacc[c]);
      }
    }
    __syncthreads();  // B3
#pragma unroll
    for (int c = 0; c < 4; ++c)
#pragma unroll
      for (int rg = 0; rg < 4; ++rg) {
        int t = wv * 16 + lg * 4 + rg;
        sK[t * LDH + c * 16 + l16] = f2bf(oacc[c][rg]);
      }
    __syncthreads();  // B4

    // ----- proj accumulate (B in regs)
    __builtin_amdgcn_s_setprio(1);
#pragma unroll
    for (int kk = 0; kk < 64; kk += 32) {
      const int slot = kk >> 5;
      bf16x8 a[4];
#pragma unroll
      for (int m = 0; m < 4; ++m)
        a[m] = ld8(&sK[(m * 16 + l16) * LDH + kk + 8 * lg]);
#pragma unroll
      for (int c = 0; c < 6; ++c)
#pragma unroll
        for (int m = 0; m < 4; ++m) pacc[m][c] = MFMA(a[m], pb[slot][c], pacc[m][c]);
    }
    __builtin_amdgcn_s_setprio(0);
  }

  // ---------- x2 = x + proj + bo ----------
  float* xo = x2 + (size_t)b * TT * CC;
#pragma unroll
  for (int m = 0; m < 4; ++m)
#pragma unroll
    for (int c = 0; c < 6; ++c) {
      int n = wv * 96 + c * 16 + l16;
      float bov = bo[n];
#pragma unroll
      for (int rg = 0; rg < 4; ++rg) {
        int t = m * 16 + lg * 4 + rg;
        xo[t * CC + n] = xb[t * CC + n] + pacc[m][c][rg] + bov;
      }
    }
}

// ---- kernel B v7: LN2 + MLP + residual; M=64, chunk=128 (12 chunks).
// R7's private glds16+counted-vmcnt staging (G1) + 2 WGs/CU occupancy + no spill.
// LDS = 48K sXN + 16K sH + 16K sW = 81920 B -> 2 WGs/CU (R3 precedent).
// __launch_bounds__(512,2) -> 256-reg cap, demand ~140: spill impossible.
__global__ __launch_bounds__(512, 2)
void mlp_fwd(const float* __restrict__ ln2g, const float* __restrict__ ln2b,
             const float* __restrict__ b1, const float* __restrict__ b2,
             const unsigned short* __restrict__ W1T,
             const unsigned short* __restrict__ W2T,
             float* xo) {
  __shared__ unsigned short sXN[24576];  // [4 m][12 sl][4 ks][16 row^ks][8] = 48 KB
  __shared__ unsigned short sH[8192];    // [4 m][ 4 sl][4 ks][16 row^ks][8] = 16 KB
  __shared__ unsigned short sW[8192];    // 8 waves x 2x[16][32] dbuf (2 KB each) = 16 KB

  const int b = blockIdx.x;
  const int tid = threadIdx.x;
  const int wv = tid >> 6;      // 0..7
  const int ln = tid & 63;
  const int l16 = ln & 15;
  const int lg = ln >> 4;
  float* xb = xo + (size_t)b * TT * CC;
  const f32x4 Z4 = {0.f, 0.f, 0.f, 0.f};
  unsigned short* myW = sW + wv * 1024;
  const int rx = (l16 ^ lg) << 3;   // conflict-free fragment-read offset (sXN/sH)

  // ---------- LN2: 8 waves x 8 rows -> k-major swizzled sXN (R10-proven) ----------
#pragma unroll 1
  for (int r = wv * 8; r < wv * 8 + 8; ++r) {
    float v[6], s = 0.f, sq = 0.f;
#pragma unroll
    for (int j = 0; j < 6; ++j) { v[j] = xb[r * CC + ln + 64 * j]; s += v[j]; sq += v[j] * v[j]; }
#pragma unroll
    for (int off = 32; off; off >>= 1) { s += __shfl_xor(s, off); sq += __shfl_xor(sq, off); }
    float mu = s * (1.f / CC);
    float rs = rsqrtf(sq * (1.f / CC) - mu * mu + 1e-5f);
    int m = r >> 4, row16 = r & 15;
#pragma unroll
    for (int j = 0; j < 6; ++j) {
      int c = ln + 64 * j;
      int sl = c >> 5, ks = (c >> 3) & 3, off = c & 7;
      sXN[(((m * 12 + sl) * 4 + ks) * 16 + (row16 ^ ks)) * 8 + off] =
          f2bf((v[j] - mu) * rs * ln2g[c] + ln2b[c]);
    }
  }
  __syncthreads();   // drains LN2 x-loads: vmcnt == 0

// G1 slice staging: [16 cols][32 k] = 1 glds16 (lane ln: row ln>>2, k (ln&3)*8; dest linear)
#define G1S(CH, SL)                                                             \
  glds16(W1T + (size_t)((CH) * 128 + wv * 16 + (ln >> 2)) * CC + (SL) * 32 +    \
             (ln & 3) * 8,                                                      \
         myW + ((SL) & 1) * 512)

// G1 slice compute: 4 A-reads (conflict-free) + 1 B-read + 4 MFMA
#define G1C(SL) do {                                                            \
    bf16x8 a_[4];                                                               \
    _Pragma("unroll")                                                           \
    for (int m = 0; m < 4; ++m)                                                 \
      a_[m] = ld8(&sXN[((m * 48 + (SL) * 4 + lg) << 7) + rx]);                  \
    bf16x8 bb_ = ld8(&myW[((SL) & 1) * 512 + l16 * 32 + lg * 8]);               \
    __builtin_amdgcn_s_setprio(1);                                              \
    _Pragma("unroll")                                                           \
    for (int m = 0; m < 4; ++m) hacc[m] = MFMA(a_[m], bb_, hacc[m]);            \
    __builtin_amdgcn_s_setprio(0);                                              \
  } while (0)

  f32x4 macc[4][3];
#pragma unroll
  for (int m = 0; m < 4; ++m)
#pragma unroll
    for (int c = 0; c < 3; ++c) macc[m][c] = Z4;

  // chunk-0 G1 prologue: slices 0,1 in flight
  G1S(0, 0); G1S(0, 1);

#pragma unroll 1
  for (int ch = 0; ch < 12; ++ch) {
    // ===== GEMM1: 12 BK-32 slices, private dbuf, steady WAITVM(1) =====
    f32x4 hacc[4];
#pragma unroll
    for (int m = 0; m < 4; ++m) hacc[m] = Z4;

    WAITVM(1); G1C(0);  G1S(ch, 2);
    WAITVM(1); G1C(1);  G1S(ch, 3);
    WAITVM(1); G1C(2);  G1S(ch, 4);
    WAITVM(1); G1C(3);  G1S(ch, 5);
    WAITVM(1); G1C(4);  G1S(ch, 6);
    WAITVM(1); G1C(5);  G1S(ch, 7);
    WAITVM(1); G1C(6);  G1S(ch, 8);
    WAITVM(1); G1C(7);  G1S(ch, 9);
    WAITVM(1); G1C(8);  G1S(ch, 10);
    WAITVM(1); G1C(9);  G1S(ch, 11);
    WAITVM(1); G1C(10);
    WAITVM(0); G1C(11);

    // G2 slice-0 B prefetch + b1 (drained by barrier A, used right after)
    float b1v = b1[ch * 128 + wv * 16 + l16];
    const unsigned short* w2p = W2T + (size_t)(wv * 48 + l16) * HID + ch * 128 + 8 * lg;
    bf16x8 c2[3];
#pragma unroll
    for (int c = 0; c < 3; ++c) c2[c] = ld8(w2p + (size_t)(c * 16) * HID);

    __syncthreads();  // A: prev chunk's G2 done reading sH

    // sH = relu(hacc + b1): wave's 16 chunk-cols x 64 rows, k-major swizzled
    {
      int nl = wv * 16 + l16;
      int slh = nl >> 5, ks = (nl >> 3) & 3, off = nl & 7;
#pragma unroll
      for (int m = 0; m < 4; ++m)
#pragma unroll
        for (int rg = 0; rg < 4; ++rg) {
          int row16 = lg * 4 + rg;
          sH[(((m * 4 + slh) * 4 + ks) * 16 + (row16 ^ ks)) * 8 + off] =
              f2bf(fmaxf(hacc[m][rg] + b1v, 0.f));
        }
    }
    __syncthreads();  // B: sH visible

    // ===== GEMM2: 4 BK-32 slices, reg-frag depth-1; cross-phase G1 staging at sl=2 =====
#pragma unroll
    for (int sl = 0; sl < 4; ++sl) {
      bf16x8 a2[4];
#pragma unroll
      for (int m = 0; m < 4; ++m)
        a2[m] = ld8(&sH[((m * 16 + sl * 4 + lg) << 7) + rx]);
      bf16x8 nxt[3];
      if (sl < 3) {
#pragma unroll
        for (int c = 0; c < 3; ++c) nxt[c] = ld8(w2p + (size_t)(c * 16) * HID + (sl + 1) * 32);
      }
      if (sl == 2 && ch < 11) {   // next-chunk G1 prologue: hides under sl2+sl3 MFMAs
        G1S(ch + 1, 0); G1S(ch + 1, 1);
      }
      __builtin_amdgcn_s_setprio(1);
#pragma unroll
      for (int c = 0; c < 3; ++c)
#pragma unroll
        for (int m = 0; m < 4; ++m) macc[m][c] = MFMA(a2[m], c2[c], macc[m][c]);
      __builtin_amdgcn_s_setprio(0);
      if (sl < 3) {
#pragma unroll
        for (int c = 0; c < 3; ++c) c2[c] = nxt[c];
      }
    }
  }

  // ---------- out = x2 + mlp + b2 (read-before-write, same buffer) ----------
#pragma unroll
  for (int m = 0; m < 4; ++m)
#pragma unroll
    for (int c = 0; c < 3; ++c) {
      int n = wv * 48 + c * 16 + l16;
      float b2v = b2[n];
#pragma unroll
      for (int rg = 0; rg < 4; ++rg) {
        int t = m * 16 + lg * 4 + rg;
        size_t idx = (size_t)t * CC + n;
        float x2v = xb[idx];
        xb[idx] = x2v + macc[m][c][rg] + b2v;
      }
    }
#undef G1S
#undef G1C
}

extern "C" void kernel_launch(void* const* d_in, const int* in_sizes, int n_in,
                              void* d_out, int out_size, void* d_ws, size_t ws_size,
                              hipStream_t stream) {
  const float* x    = (const float*)d_in[0];
  const float* ln1g = (const float*)d_in[1];
  const float* ln1b = (const float*)d_in[2];
  const float* Wq   = (const float*)d_in[3];
  const float* Wk   = (const float*)d_in[4];
  const float* Wv   = (const float*)d_in[5];
  const float* Wo   = (const float*)d_in[6];
  const float* bo   = (const float*)d_in[7];
  const float* ln2g = (const float*)d_in[8];
  const float* ln2b = (const float*)d_in[9];
  const float* W1   = (const float*)d_in[10];
  const float* b1   = (const float*)d_in[11];
  const float* W2   = (const float*)d_in[12];
  const float* b2   = (const float*)d_in[13];
  unsigned short* ws = (unsigned short*)d_ws;

  const size_t need = (size_t)(1152 * 384 + 384 * 384 + 1536 * 384 + 384 * 1536) * 2;
  if (ws_size < need) return;

  hipLaunchKernelGGL(prep_w, dim3(1024), dim3(256), 0, stream, Wq, Wk, Wv, Wo, W1, W2, ws);

  const unsigned short* Wqkv = ws;
  const unsigned short* WoT  = ws + 1152 * 384;
  const unsigned short* W1T  = WoT + 384 * 384;
  const unsigned short* W2T  = W1T + 1536 * 384;
  int nblk = in_sizes[0] / (TT * CC);

  hipLaunchKernelGGL(attn_fwd, dim3(nblk), dim3(256), 0, stream,
                     x, ln1g, ln1b, bo, Wqkv, WoT, (float*)d_out);
  hipLaunchKernelGGL(mlp_fwd, dim3(nblk), dim3(512), 0, stream,
                     ln2g, ln2b, b1, b2, W1T, W2T, (float*)d_out);
}

// Round 13
// 440.846 us; speedup vs baseline: 1.1545x; 1.1545x over previous
//
#include <hip/hip_runtime.h>

#define TT 64
#define CC 384
#define NH 6
#define HID 1536
#define LDX 392   // attn: padded cols for 64x384 bf16 tiles
#define LDH 72    // attn head tiles (144B stride)

typedef __bf16 bf16x8 __attribute__((ext_vector_type(8)));
typedef float f32x4 __attribute__((ext_vector_type(4)));
typedef unsigned short us8 __attribute__((ext_vector_type(8)));

#define MFMA(a, b, c) __builtin_amdgcn_mfma_f32_16x16x32_bf16(a, b, c, 0, 0, 0)
#define WAITVM(N) asm volatile("s_waitcnt vmcnt(" #N ")" ::: "memory")

static __device__ __forceinline__ unsigned short f2bf(float f) {
  unsigned u = __builtin_bit_cast(unsigned, f);
  u += 0x7FFFu + ((u >> 16) & 1u);
  return (unsigned short)(u >> 16);
}
static __device__ __forceinline__ float bf2f(unsigned short h) {
  unsigned u = ((unsigned)h) << 16;
  return __builtin_bit_cast(float, u);
}
static __device__ __forceinline__ bf16x8 ld8(const unsigned short* p) {
  return __builtin_bit_cast(bf16x8, *reinterpret_cast<const us8*>(p));
}
// async global->LDS, 16B per lane; lds dest = wave-uniform base + lane*16
static __device__ __forceinline__ void glds16(const unsigned short* g, unsigned short* l) {
  __builtin_amdgcn_global_load_lds(
      (const __attribute__((address_space(1))) void*)g,
      (__attribute__((address_space(3))) void*)l, 16, 0, 0);
}

// ---- weight prep: fp32 -> bf16, transposed to [n][k] for MFMA B-frags ----
__global__ void prep_w(const float* __restrict__ Wq, const float* __restrict__ Wk,
                       const float* __restrict__ Wv, const float* __restrict__ Wo,
                       const float* __restrict__ W1, const float* __restrict__ W2,
                       unsigned short* __restrict__ ws) {
  const int T0 = 1152 * 384;            // Wqkv [h*192+j][k]
  const int T1 = T0 + 384 * 384;        // WoT  [n][k]
  const int T2 = T1 + 1536 * 384;       // W1T  [n][k]
  const int T3 = T2 + 384 * 1536;       // W2T  [n][k]
  for (int i = blockIdx.x * blockDim.x + threadIdx.x; i < T3; i += gridDim.x * blockDim.x) {
    float v;
    if (i < T0) {
      int n = i / 384, k = i % 384;
      int hh = n / 192, j = n % 192;
      const float* W = (j < 64) ? Wq : (j < 128) ? Wk : Wv;
      int d = (j < 64) ? j : (j < 128) ? j - 64 : j - 128;
      v = W[((size_t)hh * 384 + k) * 64 + d];
    } else if (i < T1) {
      int i2 = i - T0; int n = i2 / 384, k = i2 % 384;
      v = Wo[(size_t)k * 384 + n];
    } else if (i < T2) {
      int i2 = i - T1; int n = i2 / 384, k = i2 % 384;
      v = W1[(size_t)k * 1536 + n];
    } else {
      int i2 = i - T2; int n = i2 / 1536, k = i2 % 1536;
      v = W2[(size_t)k * 384 + n];
    }
    ws[i] = f2bf(v);
  }
}

// ---- kernel A: LN1 + attention + per-head proj accumulation + residual -> x2 (=d_out, fp32)
__global__ __launch_bounds__(256, 2)
void attn_fwd(const float* __restrict__ x,
              const float* __restrict__ ln1g, const float* __restrict__ ln1b,
              const float* __restrict__ bo,
              const unsigned short* __restrict__ Wqkv,
              const unsigned short* __restrict__ WoT,
              float* __restrict__ x2) {
  __shared__ unsigned short sXN[TT * LDX];       // xn1 (bf16)
  __shared__ unsigned short sHEAD[3 * TT * LDH]; // q | k (later att_h) | vT
  unsigned short* sQ = sHEAD;                    // q [t][d]; later P [t][s]
  unsigned short* sK = sHEAD + TT * LDH;         // k [s][d]; later att_h [t][d]
  unsigned short* sV = sHEAD + 2 * TT * LDH;     // vT [d][s]

  const int b = blockIdx.x;
  const int tid = threadIdx.x;
  const int wv = tid >> 6;
  const int ln = tid & 63;
  const int l16 = ln & 15;
  const int lg = ln >> 4;
  const float* xb = x + (size_t)b * TT * CC;
  const f32x4 Z4 = {0.f, 0.f, 0.f, 0.f};

  // ---------- LN1 ----------
#pragma unroll 1
  for (int r = wv * 16; r < wv * 16 + 16; ++r) {
    float v[6], s = 0.f, sq = 0.f;
#pragma unroll
    for (int j = 0; j < 6; ++j) { v[j] = xb[r * CC + ln + 64 * j]; s += v[j]; sq += v[j] * v[j]; }
#pragma unroll
    for (int off = 32; off; off >>= 1) { s += __shfl_xor(s, off); sq += __shfl_xor(sq, off); }
    float mu = s * (1.f / CC);
    float rs = rsqrtf(sq * (1.f / CC) - mu * mu + 1e-5f);
#pragma unroll
    for (int j = 0; j < 6; ++j) {
      int c = ln + 64 * j;
      sXN[r * LDX + c] = f2bf((v[j] - mu) * rs * ln1g[c] + ln1b[c]);
    }
  }
  __syncthreads();

  f32x4 pacc[4][6];
#pragma unroll
  for (int m = 0; m < 4; ++m)
#pragma unroll
    for (int c = 0; c < 6; ++c) pacc[m][c] = Z4;

  const unsigned short* prow[6];
#pragma unroll
  for (int c = 0; c < 6; ++c)
    prow[c] = WoT + (size_t)(wv * 96 + c * 16 + l16) * CC + 8 * lg;

#pragma unroll 1
  for (int h = 0; h < NH; ++h) {
    const unsigned short* wrow[3];
#pragma unroll
    for (int c = 0; c < 3; ++c)
      wrow[c] = Wqkv + (size_t)(h * 192 + wv * 48 + c * 16 + l16) * CC + 8 * lg;

    f32x4 qacc[4][3];
#pragma unroll
    for (int m = 0; m < 4; ++m)
#pragma unroll
      for (int c = 0; c < 3; ++c) qacc[m][c] = Z4;

    // depth-2 B prefetch pipeline
    bf16x8 bpre[2][3];
#pragma unroll
    for (int c = 0; c < 3; ++c) bpre[0][c] = ld8(wrow[c] + 0);
#pragma unroll
    for (int c = 0; c < 3; ++c) bpre[1][c] = ld8(wrow[c] + 32);
#pragma unroll
    for (int kk = 0; kk < CC; kk += 32) {
      const int slot = (kk >> 5) & 1;
      bf16x8 bcur[3];
#pragma unroll
      for (int c = 0; c < 3; ++c) bcur[c] = bpre[slot][c];
      if (kk + 64 < CC) {
#pragma unroll
        for (int c = 0; c < 3; ++c) bpre[slot][c] = ld8(wrow[c] + kk + 64);
      }
      bf16x8 a[4];
#pragma unroll
      for (int m = 0; m < 4; ++m)
        a[m] = ld8(&sXN[(m * 16 + l16) * LDX + kk + 8 * lg]);
      __builtin_amdgcn_s_setprio(1);
#pragma unroll
      for (int c = 0; c < 3; ++c)
#pragma unroll
        for (int m = 0; m < 4; ++m) qacc[m][c] = MFMA(a[m], bcur[c], qacc[m][c]);
      __builtin_amdgcn_s_setprio(0);
    }
    __syncthreads();  // B1
    // scatter: q [t][d], k [s][d], vT [d][s]
#pragma unroll
    for (int m = 0; m < 4; ++m)
#pragma unroll
      for (int c = 0; c < 3; ++c) {
        int n = wv * 48 + c * 16 + l16;
#pragma unroll
        for (int rg = 0; rg < 4; ++rg) {
          int t = m * 16 + lg * 4 + rg;
          unsigned short bv = f2bf(qacc[m][c][rg]);
          if (n < 64) sQ[t * LDH + n] = bv;
          else if (n < 128) sK[t * LDH + (n - 64)] = bv;
          else sV[(n - 128) * LDH + t] = bv;
        }
      }
    __syncthreads();  // B2

    // ----- S = q.kT
    f32x4 sacc[4];
#pragma unroll
    for (int c = 0; c < 4; ++c) sacc[c] = Z4;
#pragma unroll
    for (int kk = 0; kk < 64; kk += 32) {
      bf16x8 a = ld8(&sQ[(wv * 16 + l16) * LDH + kk + 8 * lg]);
#pragma unroll
      for (int c = 0; c < 4; ++c) {
        bf16x8 bb = ld8(&sK[(c * 16 + l16) * LDH + kk + 8 * lg]);
        sacc[c] = MFMA(a, bb, sacc[c]);
      }
    }
    // causal softmax
#pragma unroll
    for (int rg = 0; rg < 4; ++rg) {
      int row = wv * 16 + lg * 4 + rg;
      float e[4], mx = -1e30f;
#pragma unroll
      for (int c = 0; c < 4; ++c) {
        int col = c * 16 + l16;
        float vv = sacc[c][rg] * 0.125f;
        e[c] = (col <= row) ? vv : -1e30f;
        mx = fmaxf(mx, e[c]);
      }
#pragma unroll
      for (int off = 8; off; off >>= 1) mx = fmaxf(mx, __shfl_xor(mx, off));
      float sum = 0.f;
#pragma unroll
      for (int c = 0; c < 4; ++c) {
        int col = c * 16 + l16;
        e[c] = (col <= row) ? __expf(e[c] - mx) : 0.f;
        sum += e[c];
      }
#pragma unroll
      for (int off = 8; off; off >>= 1) sum += __shfl_xor(sum, off);
      float inv = 1.f / sum;
#pragma unroll
      for (int c = 0; c < 4; ++c)
        sQ[row * LDH + c * 16 + l16] = f2bf(e[c] * inv);
    }

    // Preload ALL Wo B-frags for this head (latency hides under PV)
    bf16x8 pb[2][6];
#pragma unroll
    for (int s2 = 0; s2 < 2; ++s2)
#pragma unroll
      for (int c = 0; c < 6; ++c)
        pb[s2][c] = ld8(prow[c] + h * 64 + 32 * s2);

    // ----- out_h = P @ V
    f32x4 oacc[4];
#pragma unroll
    for (int c = 0; c < 4; ++c) oacc[c] = Z4;
#pragma unroll
    for (int kk = 0; kk < 64; kk += 32) {
      bf16x8 a = ld8(&sQ[(wv * 16 + l16) * LDH + kk + 8 * lg]);
#pragma unroll
      for (int c = 0; c < 4; ++c) {
        bf16x8 bb = ld8(&sV[(c * 16 + l16) * LDH + kk + 8 * lg]);
        oacc[c] = MFMA(a, bb, oacc[c]);
      }
    }
    __syncthreads();  // B3
#pragma unroll
    for (int c = 0; c < 4; ++c)
#pragma unroll
      for (int rg = 0; rg < 4; ++rg) {
        int t = wv * 16 + lg * 4 + rg;
        sK[t * LDH + c * 16 + l16] = f2bf(oacc[c][rg]);
      }
    __syncthreads();  // B4

    // ----- proj accumulate (B in regs)
    __builtin_amdgcn_s_setprio(1);
#pragma unroll
    for (int kk = 0; kk < 64; kk += 32) {
      const int slot = kk >> 5;
      bf16x8 a[4];
#pragma unroll
      for (int m = 0; m < 4; ++m)
        a[m] = ld8(&sK[(m * 16 + l16) * LDH + kk + 8 * lg]);
#pragma unroll
      for (int c = 0; c < 6; ++c)
#pragma unroll
        for (int m = 0; m < 4; ++m) pacc[m][c] = MFMA(a[m], pb[slot][c], pacc[m][c]);
    }
    __builtin_amdgcn_s_setprio(0);
  }

  // ---------- x2 = x + proj + bo ----------
  float* xo = x2 + (size_t)b * TT * CC;
#pragma unroll
  for (int m = 0; m < 4; ++m)
#pragma unroll
    for (int c = 0; c < 6; ++c) {
      int n = wv * 96 + c * 16 + l16;
      float bov = bo[n];
#pragma unroll
      for (int rg = 0; rg < 4; ++rg) {
        int t = m * 16 + lg * 4 + rg;
        xo[t * CC + n] = xb[t * CC + n] + pacc[m][c][rg] + bov;
      }
    }
}

// ---- kernel B v8: LN2 + MLP + residual; 256 thr / 4 WAVES / 2 WGs/CU.
// Halves per-block redundant LDS A-traffic vs 8-wave WGs; phase-diverse
// co-residency of 2 independent WGs. k-major conflict-free sXN/sH; per-wave
// glds16 W1 staging (R7 1-ahead WAITVM discipline); reg-frag W2 (wave=96 cols).
// LDS = 48K sXN + 16K sH + 16K sW = 81920 B.
__global__ __launch_bounds__(256, 2)
void mlp_fwd(const float* __restrict__ ln2g, const float* __restrict__ ln2b,
             const float* __restrict__ b1, const float* __restrict__ b2,
             const unsigned short* __restrict__ W1T,
             const unsigned short* __restrict__ W2T,
             float* xo) {
  __shared__ unsigned short sXN[24576];  // [4m][12sl][4ks][16 row^ks][8] = 48 KB
  __shared__ unsigned short sH[8192];    // [4m][ 4sl][4ks][16 row^ks][8] = 16 KB
  __shared__ unsigned short sW[8192];    // 4 waves x 2 bufs x [32c][32k] (4KB/wave) = 16 KB

  const int b = blockIdx.x;
  const int tid = threadIdx.x;
  const int wv = tid >> 6;      // 0..3
  const int ln = tid & 63;
  const int l16 = ln & 15;
  const int lg = ln >> 4;
  float* xb = xo + (size_t)b * TT * CC;
  const f32x4 Z4 = {0.f, 0.f, 0.f, 0.f};
  unsigned short* myW = sW + wv * 2048;
  const int rx = (l16 ^ lg) << 3;   // conflict-free fragment-read offset

  // ---------- LN2: 4 waves x 16 rows -> k-major swizzled sXN ----------
#pragma unroll 1
  for (int r = wv * 16; r < wv * 16 + 16; ++r) {
    float v[6], s = 0.f, sq = 0.f;
#pragma unroll
    for (int j = 0; j < 6; ++j) { v[j] = xb[r * CC + ln + 64 * j]; s += v[j]; sq += v[j] * v[j]; }
#pragma unroll
    for (int off = 32; off; off >>= 1) { s += __shfl_xor(s, off); sq += __shfl_xor(sq, off); }
    float mu = s * (1.f / CC);
    float rs = rsqrtf(sq * (1.f / CC) - mu * mu + 1e-5f);
    int m = r >> 4, row16 = r & 15;
#pragma unroll
    for (int j = 0; j < 6; ++j) {
      int c = ln + 64 * j;
      int sl = c >> 5, ks = (c >> 3) & 3, off = c & 7;
      sXN[(((m * 12 + sl) * 4 + ks) * 16 + (row16 ^ ks)) * 8 + off] =
          f2bf((v[j] - mu) * rs * ln2g[c] + ln2b[c]);
    }
  }
  __syncthreads();   // drains LN2 x-loads: vmcnt == 0

// G1 slice staging: wave's [32 cols][32 k] = 2 glds16 (lane: row ln>>2, kseg ln&3)
// dest layout [j(16rows)][row][kseg] == linear lane*16B
#define G1S(CH, SL) do {                                                        \
    _Pragma("unroll")                                                           \
    for (int j = 0; j < 2; ++j)                                                 \
      glds16(W1T + (size_t)((CH) * 128 + wv * 32 + j * 16 + (ln >> 2)) * CC +   \
                 (SL) * 32 + (ln & 3) * 8,                                      \
             myW + ((SL) & 1) * 1024 + j * 512);                                \
  } while (0)

// G1 slice compute: 4 A-reads + 2 B-reads (all conflict-free) + 8 MFMA
#define G1C(SL) do {                                                            \
    bf16x8 a_[4];                                                               \
    _Pragma("unroll")                                                           \
    for (int m = 0; m < 4; ++m)                                                 \
      a_[m] = ld8(&sXN[((m * 48 + (SL) * 4 + lg) << 7) + rx]);                  \
    __builtin_amdgcn_s_setprio(1);                                              \
    _Pragma("unroll")                                                           \
    for (int c = 0; c < 2; ++c) {                                               \
      bf16x8 bb_ = ld8(&myW[((SL) & 1) * 1024 + c * 512 + l16 * 32 + lg * 8]);  \
      _Pragma("unroll")                                                         \
      for (int m = 0; m < 4; ++m) hacc[m][c] = MFMA(a_[m], bb_, hacc[m][c]);    \
    }                                                                           \
    __builtin_amdgcn_s_setprio(0);                                              \
  } while (0)

  f32x4 macc[4][6];
#pragma unroll
  for (int m = 0; m < 4; ++m)
#pragma unroll
    for (int c = 0; c < 6; ++c) macc[m][c] = Z4;

  // W2 reg-frag base: wave owns 96 out-cols
  const unsigned short* w2base = W2T + (size_t)(wv * 96 + l16) * HID + 8 * lg;

  // chunk-0 G1 prologue
  G1S(0, 0);

#pragma unroll 1
  for (int ch = 0; ch < 12; ++ch) {
    // ===== GEMM1: 12 BK-32 slices, 1-ahead staging, steady WAITVM(2) =====
    f32x4 hacc[4][2];
#pragma unroll
    for (int m = 0; m < 4; ++m)
#pragma unroll
      for (int c = 0; c < 2; ++c) hacc[m][c] = Z4;

    G1S(ch, 1);  WAITVM(2); G1C(0);
    G1S(ch, 2);  WAITVM(2); G1C(1);
    G1S(ch, 3);  WAITVM(2); G1C(2);
    G1S(ch, 4);  WAITVM(2); G1C(3);
    G1S(ch, 5);  WAITVM(2); G1C(4);
    G1S(ch, 6);  WAITVM(2); G1C(5);
    G1S(ch, 7);  WAITVM(2); G1C(6);
    G1S(ch, 8);  WAITVM(2); G1C(7);
    G1S(ch, 9);  WAITVM(2); G1C(8);
    G1S(ch, 10); WAITVM(2); G1C(9);
    G1S(ch, 11); WAITVM(2); G1C(10);
    WAITVM(0);   G1C(11);

    // b1 + G2 slice-0 B prefetch + next-chunk G1 S0 (all drained by barrier A)
    float b1c[2];
#pragma unroll
    for (int c = 0; c < 2; ++c) b1c[c] = b1[ch * 128 + wv * 32 + c * 16 + l16];
    const unsigned short* w2p = w2base + ch * 128;
    bf16x8 c2[6];
#pragma unroll
    for (int c = 0; c < 6; ++c) c2[c] = ld8(w2p + (size_t)(c * 16) * HID);
    if (ch < 11) G1S(ch + 1, 0);

    __syncthreads();  // A: prev chunk's G2 done reading sH; drains vmcnt

    // sH = relu(hacc + b1): wave's 32 chunk-cols x 64 rows, k-major swizzled
#pragma unroll
    for (int m = 0; m < 4; ++m)
#pragma unroll
      for (int c = 0; c < 2; ++c) {
        int nl = wv * 32 + c * 16 + l16;
        int slh = nl >> 5, ks = (nl >> 3) & 3, off = nl & 7;
#pragma unroll
        for (int rg = 0; rg < 4; ++rg) {
          int row16 = lg * 4 + rg;
          sH[(((m * 4 + slh) * 4 + ks) * 16 + (row16 ^ ks)) * 8 + off] =
              f2bf(fmaxf(hacc[m][c][rg] + b1c[c], 0.f));
        }
      }
    __syncthreads();  // B: sH visible

    // ===== GEMM2: 4 BK-32 slices, wave = 96 out-cols, reg-frag depth-1 =====
#pragma unroll
    for (int sl = 0; sl < 4; ++sl) {
      bf16x8 a2[4];
#pragma unroll
      for (int m = 0; m < 4; ++m)
        a2[m] = ld8(&sH[((m * 16 + sl * 4 + lg) << 7) + rx]);
      bf16x8 nxt[6];
      if (sl < 3) {
#pragma unroll
        for (int c = 0; c < 6; ++c) nxt[c] = ld8(w2p + (size_t)(c * 16) * HID + (sl + 1) * 32);
      }
      __builtin_amdgcn_s_setprio(1);
#pragma unroll
      for (int c = 0; c < 6; ++c)
#pragma unroll
        for (int m = 0; m < 4; ++m) macc[m][c] = MFMA(a2[m], c2[c], macc[m][c]);
      __builtin_amdgcn_s_setprio(0);
      if (sl < 3) {
#pragma unroll
        for (int c = 0; c < 6; ++c) c2[c] = nxt[c];
      }
    }
  }

  // ---------- out = x2 + mlp + b2 (read-before-write, same buffer) ----------
#pragma unroll
  for (int m = 0; m < 4; ++m)
#pragma unroll
    for (int c = 0; c < 6; ++c) {
      int n = wv * 96 + c * 16 + l16;
      float b2v = b2[n];
#pragma unroll
      for (int rg = 0; rg < 4; ++rg) {
        int t = m * 16 + lg * 4 + rg;
        size_t idx = (size_t)t * CC + n;
        float x2v = xb[idx];
        xb[idx] = x2v + macc[m][c][rg] + b2v;
      }
    }
#undef G1S
#undef G1C
}

extern "C" void kernel_launch(void* const* d_in, const int* in_sizes, int n_in,
                              void* d_out, int out_size, void* d_ws, size_t ws_size,
                              hipStream_t stream) {
  const float* x    = (const float*)d_in[0];
  const float* ln1g = (const float*)d_in[1];
  const float* ln1b = (const float*)d_in[2];
  const float* Wq   = (const float*)d_in[3];
  const float* Wk   = (const float*)d_in[4];
  const float* Wv   = (const float*)d_in[5];
  const float* Wo   = (const float*)d_in[6];
  const float* bo   = (const float*)d_in[7];
  const float* ln2g = (const float*)d_in[8];
  const float* ln2b = (const float*)d_in[9];
  const float* W1   = (const float*)d_in[10];
  const float* b1   = (const float*)d_in[11];
  const float* W2   = (const float*)d_in[12];
  const float* b2   = (const float*)d_in[13];
  unsigned short* ws = (unsigned short*)d_ws;

  const size_t need = (size_t)(1152 * 384 + 384 * 384 + 1536 * 384 + 384 * 1536) * 2;
  if (ws_size < need) return;

  hipLaunchKernelGGL(prep_w, dim3(1024), dim3(256), 0, stream, Wq, Wk, Wv, Wo, W1, W2, ws);

  const unsigned short* Wqkv = ws;
  const unsigned short* WoT  = ws + 1152 * 384;
  const unsigned short* W1T  = WoT + 384 * 384;
  const unsigned short* W2T  = W1T + 1536 * 384;
  int nblk = in_sizes[0] / (TT * CC);

  hipLaunchKernelGGL(attn_fwd, dim3(nblk), dim3(256), 0, stream,
                     x, ln1g, ln1b, bo, Wqkv, WoT, (float*)d_out);
  hipLaunchKernelGGL(mlp_fwd, dim3(nblk), dim3(256), 0, stream,
                     ln2g, ln2b, b1, b2, W1T, W2T, (float*)d_out);
}